// Round 8
// baseline (2025.535 us; speedup 1.0000x reference)
//
#include <hip/hip_runtime.h>

#define SEQ   120
#define WARM  96
#define FLEN  24
#define HDIM  256

typedef __attribute__((ext_vector_type(8))) short bf16x8;
typedef __attribute__((ext_vector_type(4))) float floatx4;
typedef unsigned int uint;
typedef unsigned long long ull;

// ws layout (bytes):
//   WHI [0,512K)      bf16 frag-linear W-hi: ((tile*8+kt)*64+lane)*8+j, tile=(s*2+uc)*4+g
//   WLO [512K,1M)     same layout
//   BB  [1M,+4K)      f32 b_ih+b_hh ; WI [1M+4K,+4K) f32 W_ih col
//   BAR [1M+8K,+2K)   uint flag[rg*16+s]  (one 64B line per rg)
//   HG  [1M+16K,+4M)  uint h packed (hi<<16|lo): 2 parities x 32 rg x 16384
//   XT  [HG+4M,+960K) f32 x transposed [t][row]
#define WHI_OFF 0
#define WLO_OFF (512 * 1024)
#define BB_OFF  (1024 * 1024)
#define WI_OFF  (1024 * 1024 + 4096)
#define BAR_OFF (1024 * 1024 + 8192)
#define HG_OFF  (1024 * 1024 + 16384)
#define HG_PAR  524288
#define XT_OFF  (HG_OFF + 4 * 1024 * 1024)

#define LDS_BYTES 65536   // W-lo only

__device__ __forceinline__ short f2bf(float v) {
    unsigned u = __float_as_uint(v);
    u += 0x7FFF + ((u >> 16) & 1);              // RNE
    return (short)(u >> 16);
}
__device__ __forceinline__ float bf2f(short s) {
    return __uint_as_float(((unsigned)(unsigned short)s) << 16);
}
__device__ __forceinline__ float fast_sig(float x) {
    return 1.0f / (1.0f + __expf(-x));
}
__device__ __forceinline__ float fast_tanh(float x) {
    return 1.0f - 2.0f / (__expf(2.0f * x) + 1.0f);
}
__device__ __forceinline__ ull load_llc64(const ull* p) {
    return __hip_atomic_load(p, __ATOMIC_RELAXED, __HIP_MEMORY_SCOPE_AGENT);
}
__device__ __forceinline__ void store_llc32(uint* p, uint v) {
    __hip_atomic_store(p, v, __ATOMIC_RELAXED, __HIP_MEMORY_SCOPE_AGENT);
}

__global__ __launch_bounds__(256) void lstm_prep(
    const float* __restrict__ W_ih, const float* __restrict__ W_hh,
    const float* __restrict__ b_ih, const float* __restrict__ b_hh,
    const float* __restrict__ h0, const float* __restrict__ x,
    unsigned char* __restrict__ ws)
{
    int tid = blockIdx.x * 256 + threadIdx.x;       // grid 2048*256
    if (tid < 262144) {
        int col = tid >> 8, k = tid & 255;          // col = gate*256+unit
        float v  = W_hh[tid];
        short hi = f2bf(v);
        short lo = f2bf(v - bf2f(hi));
        int g = col >> 8, rem = col & 255;
        int s = rem >> 5, uo = rem & 31, uc = uo >> 4, n = uo & 15;
        int kt = k >> 5, kq = (k >> 3) & 3, j = k & 7;
        size_t unit = ((((size_t)(s * 2 + uc) * 4 + g) * 8 + kt) * 64 + kq * 16 + n);
        ((short*)(ws + WHI_OFF))[unit * 8 + j] = hi;
        ((short*)(ws + WLO_OFF))[unit * 8 + j] = lo;
    }
    if (tid < 524288) {                              // pack h0 -> parity 0
        int row = tid >> 8, k = tid & 255;
        float v = h0[tid];
        short hi = f2bf(v);
        short lo = f2bf(v - bf2f(hi));
        int rg = row >> 6, rt = (row >> 4) & 3, rlow = row & 15;
        int kt = k >> 5, kq = (k >> 3) & 3, kk = k & 7;
        size_t idx = (size_t)rg * 16384 +
            (size_t)(((rt * 8 + kt) * 64 + rlow + 16 * kq) * 8 + kk);
        ((uint*)(ws + HG_OFF))[idx] =
            ((uint)(unsigned short)hi << 16) | (uint)(unsigned short)lo;
    }
    if (tid < 2048 * SEQ) {                          // x -> [t][row]
        int row = tid / SEQ, tt = tid % SEQ;
        ((float*)(ws + XT_OFF))[tt * 2048 + row] = x[tid];
    }
    if (tid < 1024) {
        ((float*)(ws + BB_OFF))[tid] = b_ih[tid] + b_hh[tid];
        ((float*)(ws + WI_OFF))[tid] = W_ih[tid];
    }
    if (tid < 512) ((uint*)(ws + BAR_OFF))[tid] = 0u;
}

__global__ void __launch_bounds__(512, 2) lstm_main(
    const float* __restrict__ c0, unsigned char* __restrict__ ws,
    const float* __restrict__ fcw, const float* __restrict__ fcb,
    float* __restrict__ out)
{
    extern __shared__ char smem[];
    short* wlo_s = (short*)smem;                  // 64 KB

    const int tid  = threadIdx.x;
    const int wv   = tid >> 6, lane = tid & 63;
    const int quad = lane >> 4, nof = lane & 15;
    const int uc   = wv & 1, rt = wv >> 1;        // rt 0..3, uc 0..1
    const int blk  = blockIdx.x;
    const int s    = blk >> 5;                    // unit-slice (32 units)
    const int rg   = blk & 31;                    // row-group (64 rows)

    const float* bb = (const float*)(ws + BB_OFF);
    const float* wi = (const float*)(ws + WI_OFF);
    const float* xT = (const float*)(ws + XT_OFF);
    uint* hg   = (uint*)(ws + HG_OFF);
    uint* flg  = (uint*)(ws + BAR_OFF) + rg * 16; // flag[s] for this rg

    // ---- W-lo slice -> LDS ----
    {
        const uint4* srcw = (const uint4*)(ws + WLO_OFF) + (size_t)s * 4096;
        uint4* dstw = (uint4*)wlo_s;
        for (int i = tid; i < 4096; i += 512) dstw[i] = srcw[i];
    }
    // ---- W-hi fragments -> regs (4 gates x 8 kt) ----
    bf16x8 bhi[4][8];
    {
        const bf16x8* whif = (const bf16x8*)(ws + WHI_OFF);
        #pragma unroll
        for (int g = 0; g < 4; ++g)
            #pragma unroll
            for (int kt = 0; kt < 8; ++kt)
                bhi[g][kt] = whif[(size_t)(((s * 2 + uc) * 4 + g) * 8 + kt) * 64 + lane];
    }

    // ---- per-thread constants ----
    const int ug = s * 32 + uc * 16 + nof;        // owned hidden unit
    float bbg[4], wig[4];
    #pragma unroll
    for (int g = 0; g < 4; ++g) { bbg[g] = bb[g * 256 + ug]; wig[g] = wi[g * 256 + ug]; }
    const float fcb0 = fcb[0];
    float c[4];
    #pragma unroll
    for (int i = 0; i < 4; ++i)
        c[i] = c0[(rg * 64 + rt * 16 + quad * 4 + i) * HDIM + ug];
    const int ktu = ug >> 5, kqu = (ug >> 3) & 3, ju = ug & 7;

    __syncthreads();

    for (int t = 0; t <= SEQ; ++t) {
        const uint par = (uint)t & 1u;
        const uint* hb = hg + (size_t)par * HG_PAR + (size_t)rg * 16384;
        const bool doy = (t >= WARM);

        floatx4 acc[4];
        #pragma unroll
        for (int g = 0; g < 4; ++g) acc[g] = (floatx4){0.f, 0.f, 0.f, 0.f};
        float yp = 0.f;
        ull e[8][4];

        auto issue = [&](int idx) {
            const int ktp = (s + idx) & 7;
            if (idx > 0) {
                while (__hip_atomic_load(&flg[ktp], __ATOMIC_RELAXED,
                                         __HIP_MEMORY_SCOPE_AGENT) < (uint)t)
                    __builtin_amdgcn_s_sleep(1);
            }
            const ull* p = (const ull*)(hb + (size_t)((rt * 8 + ktp) << 9)) + lane * 4;
            e[idx][0] = load_llc64(p + 0);
            e[idx][1] = load_llc64(p + 1);
            e[idx][2] = load_llc64(p + 2);
            e[idx][3] = load_llc64(p + 3);
        };
        auto consume = [&](int idx) {
            const int ktp = (s + idx) & 7;
            uint xs[8];
            uint4 hi4, lo4;
            #pragma unroll
            for (int q = 0; q < 4; ++q) {
                ull a = e[idx][q];
                uint x0 = (uint)a, x1 = (uint)(a >> 32);
                xs[2 * q] = x0; xs[2 * q + 1] = x1;
                ((uint*)&hi4)[q] = (x0 >> 16) | (x1 & 0xFFFF0000u);
                ((uint*)&lo4)[q] = (x0 & 0xFFFFu) | (x1 << 16);
            }
            bf16x8 ah = *(bf16x8*)&hi4;
            bf16x8 al = *(bf16x8*)&lo4;
            if (doy) {
                float4 fa = *(const float4*)(fcw + ktp * 32 + quad * 8);
                float4 fb = *(const float4*)(fcw + ktp * 32 + quad * 8 + 4);
                const float fc8[8] = {fa.x, fa.y, fa.z, fa.w, fb.x, fb.y, fb.z, fb.w};
                #pragma unroll
                for (int j = 0; j < 8; ++j)
                    yp = fmaf(fc8[j], __uint_as_float(xs[j] & 0xFFFF0000u) +
                                      __uint_as_float(xs[j] << 16), yp);
            }
            #pragma unroll
            for (int g = 0; g < 4; ++g) {
                bf16x8 bl = *(const bf16x8*)(wlo_s + ((uc * 4 + g) * 8 + ktp) * 512 + lane * 8);
                acc[g] = __builtin_amdgcn_mfma_f32_16x16x32_bf16(ah, bhi[g][ktp], acc[g], 0, 0, 0);
                acc[g] = __builtin_amdgcn_mfma_f32_16x16x32_bf16(al, bhi[g][ktp], acc[g], 0, 0, 0);
                acc[g] = __builtin_amdgcn_mfma_f32_16x16x32_bf16(ah, bl,          acc[g], 0, 0, 0);
            }
        };

        issue(0); issue(1); issue(2); issue(3);
        #pragma unroll
        for (int idx = 0; idx < 8; ++idx) {
            if (idx + 4 < 8) issue(idx + 4);
            consume(idx);
        }

        // ---- y(t-1) reduce (register-only) ----
        float yv = 0.f;
        if (doy) {
            yp += __shfl_xor(yp, 16, 64);
            yp += __shfl_xor(yp, 32, 64);
            yv = yp;                              // lane L holds y[row rt*16 + (L&15)]
            if (t >= WARM + 1 && s == 0 && uc == 0 && quad == 0)
                out[(rg * 64 + rt * 16 + nof) * FLEN + (t - WARM - 1)] = yv + fcb0;
        }
        if (t == SEQ) break;

        // ---- elementwise LSTM + LLC h store ----
        float4 xv = {0.f, 0.f, 0.f, 0.f};
        if (t < WARM)
            xv = *(const float4*)(xT + t * 2048 + rg * 64 + rt * 16 + quad * 4);
        const float xin[4] = {xv.x, xv.y, xv.z, xv.w};

        uint* hdst = hg + (size_t)(1u - par) * HG_PAR + (size_t)rg * 16384;
        #pragma unroll
        for (int i = 0; i < 4; ++i) {
            const int m = quad * 4 + i;
            float inr;
            if (t < WARM) inr = xin[i];
            else          inr = __shfl(yv, quad * 4 + i, 64) + fcb0;
            float vi = acc[0][i] + bbg[0] + inr * wig[0];
            float vf = acc[1][i] + bbg[1] + inr * wig[1];
            float vg = acc[2][i] + bbg[2] + inr * wig[2];
            float vo = acc[3][i] + bbg[3] + inr * wig[3];
            float cn = fast_sig(vf) * c[i] + fast_sig(vi) * fast_tanh(vg);
            c[i] = cn;
            float h = fast_sig(vo) * fast_tanh(cn);
            short hi = f2bf(h);
            short lo = f2bf(h - bf2f(hi));
            store_llc32(hdst + (size_t)(((rt * 8 + ktu) * 64 + m + 16 * kqu) * 8 + ju),
                        ((uint)(unsigned short)hi << 16) | (uint)(unsigned short)lo);
        }
        asm volatile("s_waitcnt vmcnt(0)" ::: "memory");   // h stores at LLC
        __syncthreads();                                    // all waves stored
        if (tid == 0)
            __hip_atomic_store(&flg[s], (uint)(t + 1), __ATOMIC_RELAXED,
                               __HIP_MEMORY_SCOPE_AGENT);
    }
}

extern "C" void kernel_launch(void* const* d_in, const int* in_sizes, int n_in,
                              void* d_out, int out_size, void* d_ws, size_t ws_size,
                              hipStream_t stream) {
    const float* x    = (const float*)d_in[0];
    const float* h0   = (const float*)d_in[1];
    const float* c0   = (const float*)d_in[2];
    const float* W_ih = (const float*)d_in[3];
    const float* W_hh = (const float*)d_in[4];
    const float* b_ih = (const float*)d_in[5];
    const float* b_hh = (const float*)d_in[6];
    const float* fc_w = (const float*)d_in[7];
    const float* fc_b = (const float*)d_in[8];
    float* out = (float*)d_out;
    unsigned char* ws = (unsigned char*)d_ws;

    lstm_prep<<<2048, 256, 0, stream>>>(W_ih, W_hh, b_ih, b_hh, h0, x, ws);

    static int attr_set = 0;
    if (!attr_set) {
        (void)hipFuncSetAttribute((const void*)lstm_main,
                                  hipFuncAttributeMaxDynamicSharedMemorySize, LDS_BYTES);
        attr_set = 1;
    }
    void* args[] = {(void*)&c0, (void*)&ws, (void*)&fc_w, (void*)&fc_b, (void*)&out};
    (void)hipLaunchCooperativeKernel((const void*)lstm_main, dim3(256), dim3(512),
                                     args, LDS_BYTES, stream);
}

// Round 10
// 1051.820 us; speedup vs baseline: 1.9257x; 1.9257x over previous
//
#include <hip/hip_runtime.h>

#define SEQ   120
#define WARM  96
#define FLEN  24
#define HDIM  256

typedef __attribute__((ext_vector_type(8))) short bf16x8;
typedef __attribute__((ext_vector_type(4))) float floatx4;
typedef unsigned int uint;
typedef unsigned long long ull;

// ws layout (bytes):
//   WHI [0,512K)      bf16 frag-linear W-hi: ((tile*8+kt)*64+lane)*8+j, tile=(s*2+uc)*4+g
//   WLO [512K,1M)     same layout
//   BB  [1M,+4K)      f32 b_ih+b_hh ; WI [1M+4K,+4K) f32 W_ih col
//   BAR [1M+8K,+8K)   uint flag[rg], stride 64 uints (256 B), 32 rgs
//   HG  [1M+16K,+4M)  uint h packed (hi<<16|lo): 2 parities x 32 rg x 16384
//   XT  [HG+4M,+960K) f32 x transposed [t][row]
#define WHI_OFF 0
#define WLO_OFF (512 * 1024)
#define BB_OFF  (1024 * 1024)
#define WI_OFF  (1024 * 1024 + 4096)
#define BAR_OFF (1024 * 1024 + 8192)
#define HG_OFF  (1024 * 1024 + 16384)
#define HG_PAR  524288
#define XT_OFF  (HG_OFF + 4 * 1024 * 1024)

#define LDS_BYTES 65536   // W-lo only

__device__ __forceinline__ short f2bf(float v) {
    unsigned u = __float_as_uint(v);
    u += 0x7FFF + ((u >> 16) & 1);              // RNE
    return (short)(u >> 16);
}
__device__ __forceinline__ float bf2f(short s) {
    return __uint_as_float(((unsigned)(unsigned short)s) << 16);
}
__device__ __forceinline__ float fast_sig(float x) {
    return 1.0f / (1.0f + __expf(-x));
}
__device__ __forceinline__ float fast_tanh(float x) {
    return 1.0f - 2.0f / (__expf(2.0f * x) + 1.0f);
}
__device__ __forceinline__ ull load_llc64(const ull* p) {
    return __hip_atomic_load(p, __ATOMIC_RELAXED, __HIP_MEMORY_SCOPE_AGENT);
}
__device__ __forceinline__ void store_llc32(uint* p, uint v) {
    __hip_atomic_store(p, v, __ATOMIC_RELAXED, __HIP_MEMORY_SCOPE_AGENT);
}

__global__ __launch_bounds__(256) void lstm_prep(
    const float* __restrict__ W_ih, const float* __restrict__ W_hh,
    const float* __restrict__ b_ih, const float* __restrict__ b_hh,
    const float* __restrict__ h0, const float* __restrict__ x,
    unsigned char* __restrict__ ws)
{
    int tid = blockIdx.x * 256 + threadIdx.x;       // grid 2048*256
    if (tid < 262144) {
        int col = tid >> 8, k = tid & 255;          // col = gate*256+unit
        float v  = W_hh[tid];
        short hi = f2bf(v);
        short lo = f2bf(v - bf2f(hi));
        int g = col >> 8, rem = col & 255;
        int s = rem >> 5, uo = rem & 31, uc = uo >> 4, n = uo & 15;
        int kt = k >> 5, kq = (k >> 3) & 3, j = k & 7;
        size_t fr = ((((size_t)(s * 2 + uc) * 4 + g) * 8 + kt) * 64 + kq * 16 + n);
        ((short*)(ws + WHI_OFF))[fr * 8 + j] = hi;
        ((short*)(ws + WLO_OFF))[fr * 8 + j] = lo;
    }
    if (tid < 524288) {                              // pack h0 -> parity 0
        int row = tid >> 8, k = tid & 255;
        float v = h0[tid];
        short hi = f2bf(v);
        short lo = f2bf(v - bf2f(hi));
        int rg = row >> 6, rt = (row >> 4) & 3, rlow = row & 15;
        int kt = k >> 5, kq = (k >> 3) & 3, kk = k & 7;
        size_t idx = (size_t)rg * 16384 +
            (size_t)((((rt * 8 + kt) * 4 + kq) * 16 + rlow) * 8 + kk);
        ((uint*)(ws + HG_OFF))[idx] =
            ((uint)(unsigned short)hi << 16) | (uint)(unsigned short)lo;
    }
    if (tid < 2048 * SEQ) {                          // x -> [t][row]
        int row = tid / SEQ, tt = tid % SEQ;
        ((float*)(ws + XT_OFF))[tt * 2048 + row] = x[tid];
    }
    if (tid < 1024) {
        ((float*)(ws + BB_OFF))[tid] = b_ih[tid] + b_hh[tid];
        ((float*)(ws + WI_OFF))[tid] = W_ih[tid];
    }
    if (tid < 32) ((uint*)(ws + BAR_OFF))[tid * 64] = 0u;
}

__global__ void __launch_bounds__(512, 2) lstm_main(
    const float* __restrict__ c0, unsigned char* __restrict__ ws,
    const float* __restrict__ fcw, const float* __restrict__ fcb,
    float* __restrict__ out)
{
    extern __shared__ char smem[];
    short* wlo_s = (short*)smem;                  // 64 KB

    const int tid  = threadIdx.x;
    const int wv   = tid >> 6, lane = tid & 63;
    const int quad = lane >> 4, nof = lane & 15;
    const int uc   = wv & 1, rt = wv >> 1;        // rt 0..3, uc 0..1
    const int blk  = blockIdx.x;                  // 256 blocks
    const int s    = blk >> 5;                    // unit-slice (32 units)
    const int rg   = blk & 31;                    // row-group (64 rows)

    const float* bb = (const float*)(ws + BB_OFF);
    const float* wi = (const float*)(ws + WI_OFF);
    const float* xT = (const float*)(ws + XT_OFF);
    uint* hg  = (uint*)(ws + HG_OFF);
    uint* flg = (uint*)(ws + BAR_OFF) + rg * 64;

    // ---- W-lo slice -> LDS (64 KB) ----
    {
        const uint4* srcw = (const uint4*)(ws + WLO_OFF) + (size_t)s * 4096;
        uint4* dstw = (uint4*)wlo_s;
        for (int i = tid; i < 4096; i += 512) dstw[i] = srcw[i];
    }
    // ---- W-hi fragments -> regs/AGPRs (4 gates x 8 kt) ----
    bf16x8 bhi[4][8];
    {
        const bf16x8* whif = (const bf16x8*)(ws + WHI_OFF);
        #pragma unroll
        for (int g = 0; g < 4; ++g)
            #pragma unroll
            for (int kt = 0; kt < 8; ++kt)
                bhi[g][kt] = whif[(size_t)(((s * 2 + uc) * 4 + g) * 8 + kt) * 64 + lane];
    }

    // ---- per-thread constants ----
    const int ug = s * 32 + uc * 16 + nof;        // owned hidden unit
    float bbg[4], wig[4];
    #pragma unroll
    for (int g = 0; g < 4; ++g) { bbg[g] = bb[g * 256 + ug]; wig[g] = wi[g * 256 + ug]; }
    const float fcb0 = fcb[0];
    float c[4];
    #pragma unroll
    for (int i = 0; i < 4; ++i)
        c[i] = c0[(rg * 64 + rt * 16 + quad * 4 + i) * HDIM + ug];
    const int ktu = ug >> 5, kqu = (ug >> 3) & 3, ju = ug & 7;

    __syncthreads();

    for (int t = 0; t <= SEQ; ++t) {
        const uint par = (uint)t & 1u;
        const bool doy = (t >= WARM);

        // ---- wait for all 8 producer blocks of this rg (every wave polls) ----
        if (t > 0) {
            const uint tgt = 8u * (uint)t;
            while (__hip_atomic_load(flg, __ATOMIC_RELAXED,
                                     __HIP_MEMORY_SCOPE_AGENT) < tgt)
                __builtin_amdgcn_s_sleep(1);
        }

        // A-fragments: rows rt*16..+15, all k; chunk kt at +kt*256 (ull)
        const ull* hb = (const ull*)(hg + (size_t)par * HG_PAR + (size_t)rg * 16384)
                        + (size_t)rt * 2048 + lane * 4;

        floatx4 acc[4];
        #pragma unroll
        for (int g = 0; g < 4; ++g) acc[g] = (floatx4){0.f, 0.f, 0.f, 0.f};
        float yp = 0.f;

        // depth-2 rotating prefetch: only 8 ull regs live, static indices
        ull e0 = load_llc64(hb + 0), e1 = load_llc64(hb + 1),
            e2 = load_llc64(hb + 2), e3 = load_llc64(hb + 3);
        #pragma unroll
        for (int kt = 0; kt < 8; ++kt) {
            ull f0, f1, f2, f3;
            if (kt < 7) {
                const ull* p = hb + (kt + 1) * 256;
                f0 = load_llc64(p + 0); f1 = load_llc64(p + 1);
                f2 = load_llc64(p + 2); f3 = load_llc64(p + 3);
            }
            uint xs[8];
            xs[0] = (uint)e0; xs[1] = (uint)(e0 >> 32);
            xs[2] = (uint)e1; xs[3] = (uint)(e1 >> 32);
            xs[4] = (uint)e2; xs[5] = (uint)(e2 >> 32);
            xs[6] = (uint)e3; xs[7] = (uint)(e3 >> 32);
            uint4 hi4, lo4;
            #pragma unroll
            for (int q = 0; q < 4; ++q) {
                ((uint*)&hi4)[q] = (xs[2 * q] >> 16) | (xs[2 * q + 1] & 0xFFFF0000u);
                ((uint*)&lo4)[q] = (xs[2 * q] & 0xFFFFu) | (xs[2 * q + 1] << 16);
            }
            bf16x8 ah = *(bf16x8*)&hi4;
            bf16x8 al = *(bf16x8*)&lo4;
            if (doy) {
                float4 fa = *(const float4*)(fcw + kt * 32 + quad * 8);
                float4 fb = *(const float4*)(fcw + kt * 32 + quad * 8 + 4);
                const float fc8[8] = {fa.x, fa.y, fa.z, fa.w, fb.x, fb.y, fb.z, fb.w};
                #pragma unroll
                for (int j = 0; j < 8; ++j)
                    yp = fmaf(fc8[j], __uint_as_float(xs[j] & 0xFFFF0000u) +
                                      __uint_as_float(xs[j] << 16), yp);
            }
            #pragma unroll
            for (int g = 0; g < 4; ++g) {
                bf16x8 bl = *(const bf16x8*)(wlo_s + ((uc * 4 + g) * 8 + kt) * 512 + lane * 8);
                acc[g] = __builtin_amdgcn_mfma_f32_16x16x32_bf16(ah, bhi[g][kt], acc[g], 0, 0, 0);
                acc[g] = __builtin_amdgcn_mfma_f32_16x16x32_bf16(al, bhi[g][kt], acc[g], 0, 0, 0);
                acc[g] = __builtin_amdgcn_mfma_f32_16x16x32_bf16(ah, bl,          acc[g], 0, 0, 0);
            }
            if (kt < 7) { e0 = f0; e1 = f1; e2 = f2; e3 = f3; }
        }

        // ---- y(t-1) reduce: after xors, lane L holds y[row rt*16+(L&15)] ----
        float yv = 0.f;
        if (doy) {
            yp += __shfl_xor(yp, 16, 64);
            yp += __shfl_xor(yp, 32, 64);
            yv = yp;
            if (t >= WARM + 1 && s == 0 && uc == 0 && quad == 0)
                out[(rg * 64 + rt * 16 + nof) * FLEN + (t - WARM - 1)] = yv + fcb0;
        }
        if (t == SEQ) break;

        // ---- elementwise LSTM + LLC h store ----
        float4 xv = {0.f, 0.f, 0.f, 0.f};
        if (t < WARM)
            xv = *(const float4*)(xT + t * 2048 + rg * 64 + rt * 16 + quad * 4);
        const float xin[4] = {xv.x, xv.y, xv.z, xv.w};

        uint* hdst = hg + (size_t)(1u - par) * HG_PAR + (size_t)rg * 16384;
        #pragma unroll
        for (int i = 0; i < 4; ++i) {
            const int m = quad * 4 + i;
            float inr;
            if (t < WARM) inr = xin[i];
            else          inr = __shfl(yv, m, 64) + fcb0;
            float vi = acc[0][i] + bbg[0] + inr * wig[0];
            float vf = acc[1][i] + bbg[1] + inr * wig[1];
            float vg = acc[2][i] + bbg[2] + inr * wig[2];
            float vo = acc[3][i] + bbg[3] + inr * wig[3];
            float cn = fast_sig(vf) * c[i] + fast_sig(vi) * fast_tanh(vg);
            c[i] = cn;
            float h = fast_sig(vo) * fast_tanh(cn);
            short hi = f2bf(h);
            short lo = f2bf(h - bf2f(hi));
            store_llc32(hdst + (size_t)((((rt * 8 + ktu) * 4 + kqu) * 16 + m) * 8 + ju),
                        ((uint)(unsigned short)hi << 16) | (uint)(unsigned short)lo);
        }
        asm volatile("s_waitcnt vmcnt(0)" ::: "memory");   // h stores at LLC
        __syncthreads();                                    // all 8 waves stored
        if (tid == 0)
            __hip_atomic_fetch_add(flg, 1u, __ATOMIC_RELAXED,
                                   __HIP_MEMORY_SCOPE_AGENT);
    }
}

extern "C" void kernel_launch(void* const* d_in, const int* in_sizes, int n_in,
                              void* d_out, int out_size, void* d_ws, size_t ws_size,
                              hipStream_t stream) {
    const float* x    = (const float*)d_in[0];
    const float* h0   = (const float*)d_in[1];
    const float* c0   = (const float*)d_in[2];
    const float* W_ih = (const float*)d_in[3];
    const float* W_hh = (const float*)d_in[4];
    const float* b_ih = (const float*)d_in[5];
    const float* b_hh = (const float*)d_in[6];
    const float* fc_w = (const float*)d_in[7];
    const float* fc_b = (const float*)d_in[8];
    float* out = (float*)d_out;
    unsigned char* ws = (unsigned char*)d_ws;

    lstm_prep<<<2048, 256, 0, stream>>>(W_ih, W_hh, b_ih, b_hh, h0, x, ws);

    static int attr_set = 0;
    if (!attr_set) {
        (void)hipFuncSetAttribute((const void*)lstm_main,
                                  hipFuncAttributeMaxDynamicSharedMemorySize, LDS_BYTES);
        attr_set = 1;
    }
    void* args[] = {(void*)&c0, (void*)&ws, (void*)&fc_w, (void*)&fc_b, (void*)&out};
    (void)hipLaunchCooperativeKernel((const void*)lstm_main, dim3(256), dim3(512),
                                     args, LDS_BYTES, stream);
}